// Round 5
// baseline (180.969 us; speedup 1.0000x reference)
//
#include <hip/hip_runtime.h>
#include <hip/hip_bf16.h>
#include <stdint.h>

// MB=128, C=2048, P=32, DG=256, DF=256, DOUT=128
using short8  = __attribute__((ext_vector_type(8))) short;
using f32x4   = __attribute__((ext_vector_type(4))) float;
using f32x16  = __attribute__((ext_vector_type(16))) float;
using uint4v  = __attribute__((ext_vector_type(4))) unsigned int;

#define MFMA16(a,b,c) __builtin_amdgcn_mfma_f32_16x16x32_bf16((a),(b),(c),0,0,0)
#define MFMA32(a,b,c) __builtin_amdgcn_mfma_f32_32x32x16_bf16((a),(b),(c),0,0,0)

__device__ inline short f2bf(float f){              // RNE
  unsigned u = __float_as_uint(f);
  u += 0x7fff + ((u>>16)&1);
  return (short)(u>>16);
}
// round-half-up bf16 pair pack: bf(a) | bf(b)<<16  (2 adds + 1 v_perm)
__device__ inline unsigned pack2(float a, float b){
  return __builtin_amdgcn_perm(__float_as_uint(b) + 0x8000u,
                               __float_as_uint(a) + 0x8000u, 0x07060302u);
}

union FragU { uint4v u; short8 s; };
__device__ inline short8 mk8(unsigned w0, unsigned w1, unsigned w2, unsigned w3){
  FragU f; f.u = (uint4v){w0, w1, w2, w3}; return f.s;
}

// ---- merged prep: [0,1024) transpose x -> xfrag ; [1024,1632) weights -> frags ----
// xfrag (16x16 B-frag, k_ab): slot (b, ck, mt, kk, l, i): token = mt*16+(l&15),
//   c = ck*256 + kk*32 + (l>>4)*8 + i
// W1 (16x16 A-frag, k_ab): ((ct*64 + kk)*64 + lane)*8 + i, d = ct*16+(l&15)
// W2/3/4 (32x32 A-frag, k_heavy): ((ct*16 + kk)*64 + l)*8 + i,
//   d = ct*32 + (l&31), k = kk*16 + (l>>5)*8 + i   [layout verified by R3 k_ab pass]
__global__ __launch_bounds__(256) void k_prep(const float* __restrict__ x,
                                              short* __restrict__ xfrag,
                                              const float* __restrict__ Wg1,
                                              const float* __restrict__ Wg2,
                                              const float* __restrict__ Wg3,
                                              const float* __restrict__ Wg4,
                                              short* __restrict__ w1f,
                                              short* __restrict__ w2f,
                                              short* __restrict__ w3f,
                                              short* __restrict__ w4f){
  __shared__ float tile[256][33];
  const int bid = blockIdx.x, t = threadIdx.x;
  if (bid < 1024){
    const int ck = bid & 7, b = bid >> 3;
    const float* xb = x + (size_t)b*2048*32 + (size_t)ck*256*32;
#pragma unroll
    for (int r = 0; r < 32; r++){
      int idx = r*256 + t;            // = c_local*32 + p
      tile[idx>>5][idx&31] = xb[idx];
    }
    __syncthreads();
    short* ob = xfrag + (size_t)(b*8 + ck)*8192; // [mt][kk][l][i]
#pragma unroll
    for (int i4 = 0; i4 < 4; i4++){
      int s = i4*256 + t;             // slot: (mt, kk, l)
      int mt = s>>9, kk = (s>>6)&7, l = s&63;
      int tok = mt*16 + (l&15);
      int cb = kk*32 + (l>>4)*8;
      short8 o;
#pragma unroll
      for (int j = 0; j < 8; j++) o[j] = f2bf(tile[cb+j][tok]);
      *(short8*)(ob + (size_t)s*8) = o;
    }
  } else {
    int g = (bid - 1024)*256 + t;
    if (g < 32*64*64){
      int l = g & 63, kk = (g>>6) & 63, ct = g>>12;
      int d = ct*16 + (l&15);
      int cbase = kk*32 + (l>>4)*8;
      short* o = w1f + (size_t)g*8;
#pragma unroll
      for (int i = 0; i < 8; i++){
        int c = cbase + i;
        float v = (d < 256) ? Wg1[(size_t)c*256 + d]
                            : Wg1[(size_t)(2048 + c)*256 + (d - 256)];
        o[i] = f2bf(v);
      }
    } else {
      int g2 = g - 32*64*64;          // 0..24575
      int L = g2 / 8192;
      int r = g2 - L*8192;            // ((ct*16+kk)*64+l), ct:0..7, kk:0..15
      int l = r & 63, kk = (r>>6)&15, ct = r>>10;
      const float* W = (L==0) ? Wg2 : (L==1) ? Wg3 : Wg4;
      short* o = ((L==0) ? w2f : (L==1) ? w3f : w4f) + (size_t)r*8;
      int d = ct*32 + (l&31);
      int k0 = kk*16 + (l>>5)*8;
#pragma unroll
      for (int i = 0; i < 8; i++) o[i] = f2bf(W[(size_t)(k0+i)*256 + d]);
    }
  }
}

// ------- AB = x @ [W1a|W1b], pure streaming (no LDS, no syncs), 16x16 -------
// grid (128 b, 8 d-slices of 64), 128 thr (2 waves). Wave = 32 tok x 32 d.
// (R0 form — proven; R8's b-pairing halved TLP and regressed.)
__global__ __launch_bounds__(128) void k_ab(const short* __restrict__ xfrag,
                                            const short* __restrict__ w1f,
                                            float* __restrict__ AB){
  const int wid = threadIdx.x>>6, l = threadIdx.x&63;
  const int b = blockIdx.x;
  const int ctb = blockIdx.y*4 + wid*2;          // wave owns 2 ct (32 d)
  const int hi = l>>4, lo16 = l&15;
  f32x4 acc[2][2] = {};                          // [mt][dt]
  const short* xb = xfrag + (size_t)b*65536 + (size_t)l*8;
  const short* wb = w1f + (size_t)l*8;
#pragma unroll 1
  for (int ck = 0; ck < 8; ck++){
#pragma unroll
    for (int kk = 0; kk < 8; kk++){
      short8 af0 = *(const short8*)(xb + (size_t)ck*8192 + kk*512);
      short8 af1 = *(const short8*)(xb + (size_t)ck*8192 + 4096 + kk*512);
      short8 wf0 = *(const short8*)(wb + ((size_t)(ctb  )*64 + ck*8 + kk)*512);
      short8 wf1 = *(const short8*)(wb + ((size_t)(ctb+1)*64 + ck*8 + kk)*512);
      acc[0][0] = MFMA16(wf0, af0, acc[0][0]);
      acc[1][0] = MFMA16(wf0, af1, acc[1][0]);
      acc[0][1] = MFMA16(wf1, af0, acc[0][1]);
      acc[1][1] = MFMA16(wf1, af1, acc[1][1]);
    }
  }
#pragma unroll
  for (int mt = 0; mt < 2; mt++){
    int m = b*32 + mt*16 + lo16;
#pragma unroll
    for (int dt = 0; dt < 2; dt++){
      int d0 = (ctb+dt)*16 + hi*4;
      *(f32x4*)(AB + (size_t)m*512 + d0) = acc[mt][dt];
    }
  }
}

// ------------ heavy fused kernel: REGISTER-RESIDENT ACTIVATIONS (R10) ------------
// R6-R9 showed the LDS act round-trip is the structural limit: all 8 waves read
// identical af addresses (8x duplication), 1024 ds_read_b128/CU-layer x 12cy > MFMA
// 8.2K cy. This version: wave = one (b,q), 32 tokens x ALL 256 d. Layer output in C
// regs IS the next layer's input — act never touches LDS. LDS holds WEIGHTS instead
// (ct 0..5 staged = 96KB; ct 6,7 from L2) so neither pipe exceeds ~MFMA budget.
// Inter-layer C->B-frag transform: C(tok=l&31, d_local=gq*8+hi*4+j) -> B-frag
// (k=kk'*16+hi*8+i): own hi-quads stay, partner hi-quads via __shfl_xor(.,32).
// grid (128 b, 4 qg8), 512 thr (8 waves, q = qg8*8+w). 1 block/CU, 2 rounds.
// All frag layouts identical to the R3-verified ones; bf16 rounding via pack2 as before.
__global__ __launch_bounds__(512, 2) void k_heavy(const float* __restrict__ AB,
                                               const short* __restrict__ w2f,
                                               const short* __restrict__ w3f,
                                               const short* __restrict__ w4f,
                                               const float* __restrict__ bg1,
                                               const float* __restrict__ bg2,
                                               const float* __restrict__ bg3,
                                               const float* __restrict__ bg4,
                                               float* __restrict__ xgp){
  __shared__ short wlds[49152];                  // 96 KB: frags r<6144 (ct 0..5)
  __shared__ float part[8][256];                 // 8 KB cross-wave reduce
  const int b = blockIdx.x, qg8 = blockIdx.y, t = threadIdx.x;
  const int w = t>>6, l = t&63, tok = l&31, hi = l>>5;
  const int q = qg8*8 + w;

  // ---- stage W2 ct<6 into LDS (96KB straight copy; layout is ct-major) ----
  {
    const char* src = (const char*)w2f;
    char* dst = (char*)wlds;
#pragma unroll
    for (int i = 0; i < 12; i++){
      int off = (i*512 + t)*16;
      *(uint4v*)(dst + off) = *(const uint4v*)(src + off);
    }
  }

  // ---- build hp0 B-frags in registers: frag[kk][i] = hp0[p=tok][kk*16+hi*8+i] ----
  short8 frag[16];
  {
    const float* Ap = AB + ((size_t)(b*32) + tok)*512;
    const float* Bq = AB + ((size_t)(b*32) + q)*512 + 256;
#pragma unroll
    for (int kk = 0; kk < 16; kk++){
      int k0 = kk*16 + hi*8;
      f32x4 a0 = *(const f32x4*)(Ap + k0), a1 = *(const f32x4*)(Ap + k0 + 4);
      f32x4 q0 = *(const f32x4*)(Bq + k0), q1 = *(const f32x4*)(Bq + k0 + 4);
      f32x4 g0 = *(const f32x4*)(bg1 + k0), g1 = *(const f32x4*)(bg1 + k0 + 4);
      unsigned w0 = pack2(fmaxf(a0[0]+q0[0]+g0[0],0.f), fmaxf(a0[1]+q0[1]+g0[1],0.f));
      unsigned w1 = pack2(fmaxf(a0[2]+q0[2]+g0[2],0.f), fmaxf(a0[3]+q0[3]+g0[3],0.f));
      unsigned w2 = pack2(fmaxf(a1[0]+q1[0]+g1[0],0.f), fmaxf(a1[1]+q1[1]+g1[1],0.f));
      unsigned w3 = pack2(fmaxf(a1[2]+q1[2]+g1[2],0.f), fmaxf(a1[3]+q1[3]+g1[3],0.f));
      frag[kk] = mk8(w0, w1, w2, w3);
    }
  }
  __syncthreads();                               // wlds ready

  const short* wfr[3]  = {w2f, w3f, w4f};
  const float* bias[3] = {bg2, bg3, bg4};

#pragma unroll
  for (int L = 0; L < 3; L++){
    f32x16 acc[8];
#pragma unroll
    for (int ct = 0; ct < 8; ct++)
#pragma unroll
      for (int r = 0; r < 16; r++) acc[ct][r] = 0.f;

#pragma unroll
    for (int ct = 0; ct < 8; ct++){
#pragma unroll
      for (int kk = 0; kk < 16; kk++){
        short8 wf;
        if (ct < 6)
          wf = *(const short8*)((const char*)wlds + (((ct*16 + kk)*64 + l) << 4));
        else
          wf = *(const short8*)(wfr[L] + ((size_t)((ct*16 + kk)*64 + l))*8);
        acc[ct] = MFMA32(wf, frag[kk], acc[ct]);
      }
    }

    if (L < 2){
      __syncthreads();                           // all waves done reading wlds(L)
      // stage next layer's ct<6 (independent of transform; overlaps)
      {
        const char* src = (const char*)wfr[L+1];
        char* dst = (char*)wlds;
#pragma unroll
        for (int i = 0; i < 12; i++){
          int off = (i*512 + t)*16;
          *(uint4v*)(dst + off) = *(const uint4v*)(src + off);
        }
      }
      // in-register transform: bias+relu+bf16 pack+hi-half exchange
#pragma unroll
      for (int ct = 0; ct < 8; ct++){
        const float* bp = bias[L] + ct*32 + hi*4;
        f32x4 b0v = *(const f32x4*)(bp);
        f32x4 b1v = *(const f32x4*)(bp + 8);
        f32x4 b2v = *(const f32x4*)(bp + 16);
        f32x4 b3v = *(const f32x4*)(bp + 24);
        float t0  = fmaxf(acc[ct][ 0] + b0v[0], 0.f);
        float t1  = fmaxf(acc[ct][ 1] + b0v[1], 0.f);
        float t2  = fmaxf(acc[ct][ 2] + b0v[2], 0.f);
        float t3  = fmaxf(acc[ct][ 3] + b0v[3], 0.f);
        float t4  = fmaxf(acc[ct][ 4] + b1v[0], 0.f);
        float t5  = fmaxf(acc[ct][ 5] + b1v[1], 0.f);
        float t6  = fmaxf(acc[ct][ 6] + b1v[2], 0.f);
        float t7  = fmaxf(acc[ct][ 7] + b1v[3], 0.f);
        float t8  = fmaxf(acc[ct][ 8] + b2v[0], 0.f);
        float t9  = fmaxf(acc[ct][ 9] + b2v[1], 0.f);
        float t10 = fmaxf(acc[ct][10] + b2v[2], 0.f);
        float t11 = fmaxf(acc[ct][11] + b2v[3], 0.f);
        float t12 = fmaxf(acc[ct][12] + b3v[0], 0.f);
        float t13 = fmaxf(acc[ct][13] + b3v[1], 0.f);
        float t14 = fmaxf(acc[ct][14] + b3v[2], 0.f);
        float t15 = fmaxf(acc[ct][15] + b3v[3], 0.f);
        unsigned u0 = pack2(t0,t1),   u1 = pack2(t2,t3);     // gq0: d_local hi*4+0..3
        unsigned v0 = pack2(t4,t5),   v1 = pack2(t6,t7);     // gq1: 8+hi*4+0..3
        unsigned x0 = pack2(t8,t9),   x1 = pack2(t10,t11);   // gq2: 16+...
        unsigned y0 = pack2(t12,t13), y1 = pack2(t14,t15);   // gq3: 24+...
        unsigned eu0 = __shfl_xor(u0, 32), eu1 = __shfl_xor(u1, 32);
        unsigned ev0 = __shfl_xor(v0, 32), ev1 = __shfl_xor(v1, 32);
        unsigned ex0 = __shfl_xor(x0, 32), ex1 = __shfl_xor(x1, 32);
        unsigned ey0 = __shfl_xor(y0, 32), ey1 = __shfl_xor(y1, 32);
        // kk'=ct*2:   hi=0 needs d 0..7  = {own gq0, partner gq0}
        //             hi=1 needs d 8..15 = {partner gq1, own gq1}
        frag[ct*2    ] = mk8(hi ? ev0 : u0,  hi ? ev1 : u1,
                             hi ? v0  : eu0, hi ? v1  : eu1);
        // kk'=ct*2+1: same with gq2/gq3 (d 16..31)
        frag[ct*2 + 1] = mk8(hi ? ey0 : x0,  hi ? ey1 : x1,
                             hi ? y0  : ex0, hi ? y1  : ex1);
      }
      __syncthreads();                           // wlds(L+1) staged
    } else {
      // epilogue: bias+relu, butterfly-sum over the wave's 32 tokens,
      // then cross-wave (8 q values) reduce via LDS.
#pragma unroll
      for (int ct = 0; ct < 8; ct++){
        const float* bp = bias[2] + ct*32 + hi*4;
#pragma unroll
        for (int gq = 0; gq < 4; gq++){
          f32x4 bb = *(const f32x4*)(bp + gq*8);
          f32x4 s;
#pragma unroll
          for (int j = 0; j < 4; j++)
            s[j] = fmaxf(acc[ct][gq*4 + j] + bb[j], 0.f);
#pragma unroll
          for (int off = 1; off < 32; off <<= 1){
            s[0] += __shfl_xor(s[0], off);
            s[1] += __shfl_xor(s[1], off);
            s[2] += __shfl_xor(s[2], off);
            s[3] += __shfl_xor(s[3], off);
          }
          if (tok == 0)
            *(f32x4*)(&part[w][ct*32 + gq*8 + hi*4]) = s;
        }
      }
      __syncthreads();
      if (t < 256){
        float s = 0.f;
#pragma unroll
        for (int ww = 0; ww < 8; ww++) s += part[ww][t];
        xgp[((size_t)b*4 + qg8)*256 + t] = s;
      }
    }
  }
}

// ---------------- final tiny MLP, fp32, 512 thr, 2-way c-split ----------------
__global__ __launch_bounds__(512) void k_final(const float* __restrict__ xgp,
                                               const float* __restrict__ Wf1,
                                               const float* __restrict__ bf1,
                                               const float* __restrict__ Wfc2,
                                               const float* __restrict__ bfc2,
                                               const float* __restrict__ Wfc3,
                                               const float* __restrict__ bfc3,
                                               float* __restrict__ out){
  __shared__ float b0[256], b1[256], b2[256], part[2][256], part3[4][128];
  const int b = blockIdx.x, t = threadIdx.x;
  if (t < 256){
    float s = 0.f;
#pragma unroll
    for (int g = 0; g < 4; g++) s += xgp[((size_t)b*4 + g)*256 + t];
    b0[t] = s;
  }
  __syncthreads();
  const int d = t & 255, cg = t >> 8;
  {
    float a = cg ? 0.f : bf1[d];
#pragma unroll 8
    for (int c = cg*128; c < cg*128 + 128; c++) a += b0[c] * Wf1[c*256 + d];
    part[cg][d] = a;
  }
  __syncthreads();
  if (t < 256) b1[t] = fmaxf(part[0][t] + part[1][t], 0.f);
  __syncthreads();
  {
    float a = cg ? 0.f : bfc2[d];
#pragma unroll 8
    for (int c = cg*128; c < cg*128 + 128; c++) a += b1[c] * Wfc2[c*256 + d];
    part[cg][d] = a;
  }
  __syncthreads();
  if (t < 256) b2[t] = fmaxf(part[0][t] + part[1][t], 0.f);
  __syncthreads();
  {
    const int d3 = t & 127, cg3 = t >> 7;
    float o = cg3 ? 0.f : bfc3[d3];
#pragma unroll 8
    for (int c = cg3*64; c < cg3*64 + 64; c++) o += b2[c] * Wfc3[c*128 + d3];
    part3[cg3][d3] = o;
  }
  __syncthreads();
  if (t < 128)
    out[(size_t)b*128 + t] = part3[0][t] + part3[1][t] + part3[2][t] + part3[3][t];
}

extern "C" void kernel_launch(void* const* d_in, const int* in_sizes, int n_in,
                              void* d_out, int out_size, void* d_ws, size_t ws_size,
                              hipStream_t stream){
  const float* x    = (const float*)d_in[0];
  const float* Wg1  = (const float*)d_in[1];
  const float* bg1  = (const float*)d_in[2];
  const float* Wg2  = (const float*)d_in[3];
  const float* bg2  = (const float*)d_in[4];
  const float* Wg3  = (const float*)d_in[5];
  const float* bg3  = (const float*)d_in[6];
  const float* Wg4  = (const float*)d_in[7];
  const float* bg4  = (const float*)d_in[8];
  const float* Wf1  = (const float*)d_in[9];
  const float* bf1  = (const float*)d_in[10];
  const float* Wfc2 = (const float*)d_in[11];
  const float* bfc2 = (const float*)d_in[12];
  const float* Wfc3 = (const float*)d_in[13];
  const float* bfc3 = (const float*)d_in[14];
  float* out = (float*)d_out;

  char* ws = (char*)d_ws;
  short* xfrag = (short*)(ws);                   // 16 MB, dead after k_ab
  short* w1f   = (short*)(ws + 16777216);        // 2 MB, dead after k_ab
  short* w2f   = (short*)(ws + 18874368);        // 128 KB
  short* w3f   = (short*)(ws + 19005440);        // 128 KB
  short* w4f   = (short*)(ws + 19136512);        // 128 KB
  float* AB    = (float*)(ws + 19267584);        // 4096*512 f32 = 8 MB
  float* xgp   = (float*)(ws + 16777216);        // 512 KB, aliases dead w1f

  k_prep<<<1632, 256, 0, stream>>>(x, xfrag, Wg1, Wg2, Wg3, Wg4, w1f, w2f, w3f, w4f);
  k_ab<<<dim3(128,8), 128, 0, stream>>>(xfrag, w1f, AB);
  k_heavy<<<dim3(128,4), 512, 0, stream>>>(AB, w2f, w3f, w4f, bg1, bg2, bg3, bg4, xgp);
  k_final<<<128, 512, 0, stream>>>(xgp, Wf1, bf1, Wfc2, bfc2, Wfc3, bfc3, out);
}

// Round 6
// 114.855 us; speedup vs baseline: 1.5756x; 1.5756x over previous
//
#include <hip/hip_runtime.h>
#include <hip/hip_bf16.h>
#include <stdint.h>

// MB=128, C=2048, P=32, DG=256, DF=256, DOUT=128
using short8  = __attribute__((ext_vector_type(8))) short;
using f32x4   = __attribute__((ext_vector_type(4))) float;
using f32x16  = __attribute__((ext_vector_type(16))) float;
using uint4v  = __attribute__((ext_vector_type(4))) unsigned int;

#define MFMA16(a,b,c) __builtin_amdgcn_mfma_f32_16x16x32_bf16((a),(b),(c),0,0,0)
#define MFMA32(a,b,c) __builtin_amdgcn_mfma_f32_32x32x16_bf16((a),(b),(c),0,0,0)
// 4-bit XOR swizzle on 16B slots within 512B rows (proven: conflicts ~1M, free)
#define SWZ15(row, byteoff) ((byteoff) ^ (((row)&15)<<4))

__device__ inline short f2bf(float f){              // RNE
  unsigned u = __float_as_uint(f);
  u += 0x7fff + ((u>>16)&1);
  return (short)(u>>16);
}
// round-half-up bf16 pair pack: bf(a) | bf(b)<<16  (2 adds + 1 v_perm)
__device__ inline unsigned pack2(float a, float b){
  return __builtin_amdgcn_perm(__float_as_uint(b) + 0x8000u,
                               __float_as_uint(a) + 0x8000u, 0x07060302u);
}

// ---- merged prep: [0,1024) transpose x -> xfrag ; [1024,1632) weights -> frags ----
// xfrag (16x16 B-frag, k_ab): slot (b, ck, mt, kk, l, i): token = mt*16+(l&15),
//   c = ck*256 + kk*32 + (l>>4)*8 + i
// W1 (16x16 A-frag, k_ab): ((ct*64 + kk)*64 + lane)*8 + i, d = ct*16+(l&15)
// W2/3/4 (32x32 A-frag, k_heavy): ((ct*16 + kk)*64 + l)*8 + i,
//   d = ct*32 + (l&31), k = kk*16 + (l>>5)*8 + i   [layout verified by R3 k_ab pass]
__global__ __launch_bounds__(256) void k_prep(const float* __restrict__ x,
                                              short* __restrict__ xfrag,
                                              const float* __restrict__ Wg1,
                                              const float* __restrict__ Wg2,
                                              const float* __restrict__ Wg3,
                                              const float* __restrict__ Wg4,
                                              short* __restrict__ w1f,
                                              short* __restrict__ w2f,
                                              short* __restrict__ w3f,
                                              short* __restrict__ w4f){
  __shared__ float tile[256][33];
  const int bid = blockIdx.x, t = threadIdx.x;
  if (bid < 1024){
    const int ck = bid & 7, b = bid >> 3;
    const float* xb = x + (size_t)b*2048*32 + (size_t)ck*256*32;
#pragma unroll
    for (int r = 0; r < 32; r++){
      int idx = r*256 + t;            // = c_local*32 + p
      tile[idx>>5][idx&31] = xb[idx];
    }
    __syncthreads();
    short* ob = xfrag + (size_t)(b*8 + ck)*8192; // [mt][kk][l][i]
#pragma unroll
    for (int i4 = 0; i4 < 4; i4++){
      int s = i4*256 + t;             // slot: (mt, kk, l)
      int mt = s>>9, kk = (s>>6)&7, l = s&63;
      int tok = mt*16 + (l&15);
      int cb = kk*32 + (l>>4)*8;
      short8 o;
#pragma unroll
      for (int j = 0; j < 8; j++) o[j] = f2bf(tile[cb+j][tok]);
      *(short8*)(ob + (size_t)s*8) = o;
    }
  } else {
    int g = (bid - 1024)*256 + t;
    if (g < 32*64*64){
      int l = g & 63, kk = (g>>6) & 63, ct = g>>12;
      int d = ct*16 + (l&15);
      int cbase = kk*32 + (l>>4)*8;
      short* o = w1f + (size_t)g*8;
#pragma unroll
      for (int i = 0; i < 8; i++){
        int c = cbase + i;
        float v = (d < 256) ? Wg1[(size_t)c*256 + d]
                            : Wg1[(size_t)(2048 + c)*256 + (d - 256)];
        o[i] = f2bf(v);
      }
    } else {
      int g2 = g - 32*64*64;          // 0..24575
      int L = g2 / 8192;
      int r = g2 - L*8192;            // ((ct*16+kk)*64+l), ct:0..7, kk:0..15
      int l = r & 63, kk = (r>>6)&15, ct = r>>10;
      const float* W = (L==0) ? Wg2 : (L==1) ? Wg3 : Wg4;
      short* o = ((L==0) ? w2f : (L==1) ? w3f : w4f) + (size_t)r*8;
      int d = ct*32 + (l&31);
      int k0 = kk*16 + (l>>5)*8;
#pragma unroll
      for (int i = 0; i < 8; i++) o[i] = f2bf(W[(size_t)(k0+i)*256 + d]);
    }
  }
}

// ------- AB = x @ [W1a|W1b], pure streaming (no LDS, no syncs), 16x16 -------
// grid (128 b, 8 d-slices of 64), 128 thr (2 waves). Wave = 32 tok x 32 d.
// (R0 form — proven. R8's b-pairing halved TLP and regressed; reverted.)
__global__ __launch_bounds__(128) void k_ab(const short* __restrict__ xfrag,
                                            const short* __restrict__ w1f,
                                            float* __restrict__ AB){
  const int wid = threadIdx.x>>6, l = threadIdx.x&63;
  const int b = blockIdx.x;
  const int ctb = blockIdx.y*4 + wid*2;          // wave owns 2 ct (32 d)
  const int hi = l>>4, lo16 = l&15;
  f32x4 acc[2][2] = {};                          // [mt][dt]
  const short* xb = xfrag + (size_t)b*65536 + (size_t)l*8;
  const short* wb = w1f + (size_t)l*8;
#pragma unroll 1
  for (int ck = 0; ck < 8; ck++){
#pragma unroll
    for (int kk = 0; kk < 8; kk++){
      short8 af0 = *(const short8*)(xb + (size_t)ck*8192 + kk*512);
      short8 af1 = *(const short8*)(xb + (size_t)ck*8192 + 4096 + kk*512);
      short8 wf0 = *(const short8*)(wb + ((size_t)(ctb  )*64 + ck*8 + kk)*512);
      short8 wf1 = *(const short8*)(wb + ((size_t)(ctb+1)*64 + ck*8 + kk)*512);
      acc[0][0] = MFMA16(wf0, af0, acc[0][0]);
      acc[1][0] = MFMA16(wf0, af1, acc[1][0]);
      acc[0][1] = MFMA16(wf1, af0, acc[0][1]);
      acc[1][1] = MFMA16(wf1, af1, acc[1][1]);
    }
  }
#pragma unroll
  for (int mt = 0; mt < 2; mt++){
    int m = b*32 + mt*16 + lo16;
#pragma unroll
    for (int dt = 0; dt < 2; dt++){
      int d0 = (ctb+dt)*16 + hi*4;
      *(f32x4*)(AB + (size_t)m*512 + d0) = acc[mt][dt];
    }
  }
}

// ---------------- heavy fused kernel: hp0 init + 3 layers + token-sum ----------------
// grid (128 b, 8 qg), 512 thr (8 waves). act[128 m][256 d] bf16 SWZ15 = 64 KB.
// R11: PROVEN R0 body, restored verbatim. Grid (b=x, qg=y) keeps R8's XCD locality
// (wgid%8 = b%8 -> all 8 qg siblings of a batch share one XCD L2; FETCH 20->5.7MB).
// Sole addition vs R0: s_setprio(1/0) bracketing the kk loop (T5) — never tested in
// isolation here; prerequisite (wave role diversity) holds: 2 independent blocks/CU
// at staggered phases. No registers, no layout, no fences touched.
// Structural post-mortem (R6-R10): wf amortization 4 MFMA/load is the binding knob;
// every retile that lowers it (R6/R9) or adds register state (R7/R10) regressed.
// C layout (R3-verified): col = token = l&31, row d = (r&3) + 8*(r>>2) + 4*(l>>5).
__global__ __launch_bounds__(512) void k_heavy(const float* __restrict__ AB,
                                               const short* __restrict__ w2f,
                                               const short* __restrict__ w3f,
                                               const short* __restrict__ w4f,
                                               const float* __restrict__ bg1,
                                               const float* __restrict__ bg2,
                                               const float* __restrict__ bg3,
                                               const float* __restrict__ bg4,
                                               float* __restrict__ xgp){
  __shared__ short act[128*256];                 // 64 KB
  const int b = blockIdx.x, qg = blockIdx.y, t = threadIdx.x;
  char* abase = (char*)act;

  // hp0[m][d] = relu(A[b,p,d] + B[b,q,d] + bg1[d]);  m = ql*32+p, q = qg*4+ql
#pragma unroll
  for (int it = 0; it < 8; it++){
    int ch = it*512 + t;                         // 4096 chunks of 8 cols
    int m = ch>>5, c0 = (ch&31)*8;
    int q = qg*4 + (m>>5), p = m&31;
    const float* Ap = AB + (size_t)(b*32+p)*512 + c0;
    const float* Bp = AB + (size_t)(b*32+q)*512 + 256 + c0;
    f32x4 a0 = *(const f32x4*)Ap,       a1 = *(const f32x4*)(Ap+4);
    f32x4 b0 = *(const f32x4*)Bp,       b1 = *(const f32x4*)(Bp+4);
    f32x4 g0 = *(const f32x4*)(bg1+c0), g1 = *(const f32x4*)(bg1+c0+4);
    uint4v w;
    w[0] = pack2(fmaxf(a0[0]+b0[0]+g0[0],0.f), fmaxf(a0[1]+b0[1]+g0[1],0.f));
    w[1] = pack2(fmaxf(a0[2]+b0[2]+g0[2],0.f), fmaxf(a0[3]+b0[3]+g0[3],0.f));
    w[2] = pack2(fmaxf(a1[0]+b1[0]+g1[0],0.f), fmaxf(a1[1]+b1[1]+g1[1],0.f));
    w[3] = pack2(fmaxf(a1[2]+b1[2]+g1[2],0.f), fmaxf(a1[3]+b1[3]+g1[3],0.f));
    *(uint4v*)(abase + SWZ15(m, m*512 + c0*2)) = w;
  }
  __syncthreads();

  const int w = t>>6, l = t&63;
  const int tok = l&31, hi = l>>5;               // C col = token, hi picks d+4
  const short* wfr[3]  = {w2f, w3f, w4f};
  const float* bias[3] = {bg2, bg3, bg4};

#pragma unroll
  for (int L = 0; L < 3; L++){
    const short* wp = wfr[L] + ((size_t)(w*16)*64 + l)*8;   // ct=w; + kk*512 shorts
    f32x16 acc[4];                               // [mt], bias folded into C-in
#pragma unroll
    for (int gq = 0; gq < 4; gq++){
      f32x4 bb = *(const f32x4*)(bias[L] + w*32 + gq*8 + hi*4);
#pragma unroll
      for (int j = 0; j < 4; j++){
        float v = bb[j];
#pragma unroll
        for (int mt = 0; mt < 4; mt++) acc[mt][gq*4+j] = v;
      }
    }
    __builtin_amdgcn_s_setprio(1);
#pragma unroll
    for (int kk = 0; kk < 16; kk++){
      short8 wf = *(const short8*)(wp + (size_t)kk*512);
      short8 af[4];
#pragma unroll
      for (int mt = 0; mt < 4; mt++){
        int m = mt*32 + tok;
        af[mt] = *(const short8*)(abase + SWZ15(m, m*512 + kk*32 + hi*16));
      }
#pragma unroll
      for (int mt = 0; mt < 4; mt++)
        acc[mt] = MFMA32(wf, af[mt], acc[mt]);
    }
    __builtin_amdgcn_s_setprio(0);

    if (L < 2){
      __syncthreads();                           // all reads done before overwrite
#pragma unroll
      for (int mt = 0; mt < 4; mt++){
        int m = mt*32 + tok;
#pragma unroll
        for (int gq = 0; gq < 4; gq++){
          int d0 = w*32 + gq*8 + hi*4;
          unsigned lo2 = pack2(fmaxf(acc[mt][gq*4+0],0.f), fmaxf(acc[mt][gq*4+1],0.f));
          unsigned hi2 = pack2(fmaxf(acc[mt][gq*4+2],0.f), fmaxf(acc[mt][gq*4+3],0.f));
          *(uint2*)(abase + SWZ15(m, m*512 + d0*2)) = make_uint2(lo2, hi2);
        }
      }
      __syncthreads();
    } else {
      // relu (bias in acc), sum over all 128 tokens: 4 mt in regs,
      // then butterfly over the 32 token lanes (bits 0-4; hi untouched).
#pragma unroll
      for (int gq = 0; gq < 4; gq++){
        int d0 = w*32 + gq*8 + hi*4;
        f32x4 s;
#pragma unroll
        for (int j = 0; j < 4; j++){
          float v = fmaxf(acc[0][gq*4+j],0.f) + fmaxf(acc[1][gq*4+j],0.f)
                  + fmaxf(acc[2][gq*4+j],0.f) + fmaxf(acc[3][gq*4+j],0.f);
          s[j] = v;
        }
#pragma unroll
        for (int off = 1; off < 32; off <<= 1){
          s[0] += __shfl_xor(s[0], off);
          s[1] += __shfl_xor(s[1], off);
          s[2] += __shfl_xor(s[2], off);
          s[3] += __shfl_xor(s[3], off);
        }
        if (tok == 0)
          *(f32x4*)(xgp + ((size_t)b*8 + qg)*256 + d0) = s;
      }
    }
  }
}

// ---------------- final tiny MLP, fp32, 512 thr, 2-way c-split ----------------
__global__ __launch_bounds__(512) void k_final(const float* __restrict__ xgp,
                                               const float* __restrict__ Wf1,
                                               const float* __restrict__ bf1,
                                               const float* __restrict__ Wfc2,
                                               const float* __restrict__ bfc2,
                                               const float* __restrict__ Wfc3,
                                               const float* __restrict__ bfc3,
                                               float* __restrict__ out){
  __shared__ float b0[256], b1[256], b2[256], part[2][256], part3[4][128];
  const int b = blockIdx.x, t = threadIdx.x;
  if (t < 256){
    float s = 0.f;
#pragma unroll
    for (int g = 0; g < 8; g++) s += xgp[((size_t)b*8 + g)*256 + t];
    b0[t] = s;
  }
  __syncthreads();
  const int d = t & 255, cg = t >> 8;
  {
    float a = cg ? 0.f : bf1[d];
#pragma unroll 8
    for (int c = cg*128; c < cg*128 + 128; c++) a += b0[c] * Wf1[c*256 + d];
    part[cg][d] = a;
  }
  __syncthreads();
  if (t < 256) b1[t] = fmaxf(part[0][t] + part[1][t], 0.f);
  __syncthreads();
  {
    float a = cg ? 0.f : bfc2[d];
#pragma unroll 8
    for (int c = cg*128; c < cg*128 + 128; c++) a += b1[c] * Wfc2[c*256 + d];
    part[cg][d] = a;
  }
  __syncthreads();
  if (t < 256) b2[t] = fmaxf(part[0][t] + part[1][t], 0.f);
  __syncthreads();
  {
    const int d3 = t & 127, cg3 = t >> 7;
    float o = cg3 ? 0.f : bfc3[d3];
#pragma unroll 8
    for (int c = cg3*64; c < cg3*64 + 64; c++) o += b2[c] * Wfc3[c*128 + d3];
    part3[cg3][d3] = o;
  }
  __syncthreads();
  if (t < 128)
    out[(size_t)b*128 + t] = part3[0][t] + part3[1][t] + part3[2][t] + part3[3][t];
}

extern "C" void kernel_launch(void* const* d_in, const int* in_sizes, int n_in,
                              void* d_out, int out_size, void* d_ws, size_t ws_size,
                              hipStream_t stream){
  const float* x    = (const float*)d_in[0];
  const float* Wg1  = (const float*)d_in[1];
  const float* bg1  = (const float*)d_in[2];
  const float* Wg2  = (const float*)d_in[3];
  const float* bg2  = (const float*)d_in[4];
  const float* Wg3  = (const float*)d_in[5];
  const float* bg3  = (const float*)d_in[6];
  const float* Wg4  = (const float*)d_in[7];
  const float* bg4  = (const float*)d_in[8];
  const float* Wf1  = (const float*)d_in[9];
  const float* bf1  = (const float*)d_in[10];
  const float* Wfc2 = (const float*)d_in[11];
  const float* bfc2 = (const float*)d_in[12];
  const float* Wfc3 = (const float*)d_in[13];
  const float* bfc3 = (const float*)d_in[14];
  float* out = (float*)d_out;

  char* ws = (char*)d_ws;
  short* xfrag = (short*)(ws);                   // 16 MB, dead after k_ab
  short* w1f   = (short*)(ws + 16777216);        // 2 MB, dead after k_ab
  short* w2f   = (short*)(ws + 18874368);        // 128 KB
  short* w3f   = (short*)(ws + 19005440);        // 128 KB
  short* w4f   = (short*)(ws + 19136512);        // 128 KB
  float* AB    = (float*)(ws + 19267584);        // 4096*512 f32 = 8 MB
  float* xgp   = (float*)(ws + 16777216);        // 1 MB, aliases dead w1f

  k_prep<<<1632, 256, 0, stream>>>(x, xfrag, Wg1, Wg2, Wg3, Wg4, w1f, w2f, w3f, w4f);
  k_ab<<<dim3(128,8), 128, 0, stream>>>(xfrag, w1f, AB);
  k_heavy<<<dim3(128,8), 512, 0, stream>>>(AB, w2f, w3f, w4f, bg1, bg2, bg3, bg4, xgp);
  k_final<<<128, 512, 0, stream>>>(xgp, Wf1, bf1, Wfc2, bfc2, Wfc3, bfc3, out);
}